// Round 6
// baseline (2398.466 us; speedup 1.0000x reference)
//
#include <hip/hip_runtime.h>
#include <hip/hip_bf16.h>

#define N_ 8192
#define I_ 1024
#define O_ 1024
#define P_ 8
#define C_ 64
#define OP_ (O_ * P_)
#define WL_CAP (1u << 18)

typedef float f32x4 __attribute__((ext_vector_type(4)));
typedef __bf16 bf16x8 __attribute__((ext_vector_type(8)));
typedef unsigned short ushort8 __attribute__((ext_vector_type(8)));

#define GLOBAL_AS(p) ((const __attribute__((address_space(1))) unsigned int*)(p))
#define LDS_AS(p) ((__attribute__((address_space(3))) unsigned int*)(p))

// ---------------------------------------------------------------------------
// Kernel A0: proto_sq[o*8+p] = sum_c protos[o,p,c]^2  (fp32, exact as before)
// ---------------------------------------------------------------------------
__global__ void psq_kernel(const float* __restrict__ protos, float* __restrict__ psq) {
    const int idx = blockIdx.x * 256 + threadIdx.x;  // 0..8191
    const float* pr = protos + (size_t)idx * C_;
    float s = 0.f;
    #pragma unroll
    for (int c = 0; c < C_; ++c) s = fmaf(pr[c], pr[c], s);
    psq[idx] = s;
}

// ---------------------------------------------------------------------------
// Kernel S: split fp32 -> bf16 hi + lo (x = hi + lo + O(2^-17 x)).
// ---------------------------------------------------------------------------
__global__ __launch_bounds__(256)
void split_bf16_kernel(const float* __restrict__ src, unsigned short* __restrict__ hi,
                       unsigned short* __restrict__ lo) {
    const int idx = blockIdx.x * 256 + threadIdx.x;  // one 8-float chunk
    const float* sp = src + (size_t)idx * 8;
    const float4 f0 = *(const float4*)(sp);
    const float4 f1 = *(const float4*)(sp + 4);
    float f[8] = {f0.x, f0.y, f0.z, f0.w, f1.x, f1.y, f1.z, f1.w};
    ushort8 vh, vl;
    #pragma unroll
    for (int e = 0; e < 8; ++e) {
        const __hip_bfloat16 h = __float2bfloat16(f[e]);
        const __hip_bfloat16 l = __float2bfloat16(f[e] - __bfloat162float(h));
        vh[e] = __builtin_bit_cast(unsigned short, h);
        vl[e] = __builtin_bit_cast(unsigned short, l);
    }
    *(ushort8*)(hi + (size_t)idx * 8) = vh;
    *(ushort8*)(lo + (size_t)idx * 8) = vl;
}

// ---------------------------------------------------------------------------
// Kernel A: argmin via split-bf16 MFMA. cross = Ah*Bh + Ah*Bl + Al*Bh.
// Block 256 thr (4 waves): tile 128 op x 128 n; wave covers 128 op x 32 n.
// Direct global->register fragment loads (data L2-resident, no LDS).
// D layout (16x16x32): col=lane&15 (n), row=(lane>>4)*4+reg (op).
// Margin < 0.03 -> worklist -> exact fp64 refine (same semantics as r3-r5).
// ---------------------------------------------------------------------------
__global__ __launch_bounds__(256, 2)
void argmin_mfma_kernel(const unsigned short* __restrict__ ph, const unsigned short* __restrict__ pl,
                        const unsigned short* __restrict__ ch, const unsigned short* __restrict__ cl,
                        const float* __restrict__ psq, unsigned char* __restrict__ best,
                        unsigned* __restrict__ wl, unsigned* __restrict__ wl_cnt) {
    const int tid = threadIdx.x;
    const int w = tid >> 6, l = tid & 63;
    const int op0 = blockIdx.x * 128;
    const int nw = blockIdx.y * 128 + w * 32;
    const int lr = l & 15, lk = l >> 4;

    f32x4 acc[8][2];
    #pragma unroll
    for (int of = 0; of < 8; ++of)
        #pragma unroll
        for (int nf = 0; nf < 2; ++nf) acc[of][nf] = (f32x4)(0.f);

    #pragma unroll
    for (int ks = 0; ks < 2; ++ks) {
        const int ko = ks * 32 + lk * 8;
        bf16x8 Ah[8], Al[8], Bh[2], Bl[2];
        #pragma unroll
        for (int of = 0; of < 8; ++of) {
            const size_t r = (size_t)(op0 + of * 16 + lr) * C_ + ko;
            Ah[of] = *(const bf16x8*)(ph + r);
            Al[of] = *(const bf16x8*)(pl + r);
        }
        #pragma unroll
        for (int nf = 0; nf < 2; ++nf) {
            const size_t r = (size_t)(nw + nf * 16 + lr) * C_ + ko;
            Bh[nf] = *(const bf16x8*)(ch + r);
            Bl[nf] = *(const bf16x8*)(cl + r);
        }
        #pragma unroll
        for (int of = 0; of < 8; ++of)
            #pragma unroll
            for (int nf = 0; nf < 2; ++nf) {
                acc[of][nf] = __builtin_amdgcn_mfma_f32_16x16x32_bf16(Ah[of], Bh[nf], acc[of][nf], 0, 0, 0);
                acc[of][nf] = __builtin_amdgcn_mfma_f32_16x16x32_bf16(Ah[of], Bl[nf], acc[of][nf], 0, 0, 0);
                acc[of][nf] = __builtin_amdgcn_mfma_f32_16x16x32_bf16(Al[of], Bh[nf], acc[of][nf], 0, 0, 0);
            }
    }

    // epilogue: lane's 4 rows = lk*4+j of each 16-op frag; combine with lk^1
    // partner via shfl_xor(16) to assemble all 8 p of one o; lk even writes.
    #pragma unroll
    for (int of = 0; of < 8; ++of) {
        const int oprow0 = op0 + of * 16;
        const f32x4 ps = *(const f32x4*)(psq + oprow0 + lk * 4);
        #pragma unroll
        for (int nf = 0; nf < 2; ++nf) {
            float d[4], e[4];
            #pragma unroll
            for (int j = 0; j < 4; ++j) {
                d[j] = fmaf(-2.f, acc[of][nf][j], ps[j]);
                e[j] = __shfl_xor(d[j], 16, 64);
            }
            float v[8];
            const int po = (lk & 1) * 4;
            #pragma unroll
            for (int j = 0; j < 4; ++j) { v[po + j] = d[j]; v[(po ^ 4) + j] = e[j]; }
            float b1v = 3.4e38f, b2v = 3.4e38f;
            int bi = 0;
            #pragma unroll
            for (int p = 0; p < 8; ++p) {
                if (v[p] < b1v) { b2v = b1v; b1v = v[p]; bi = p; }
                else if (v[p] < b2v) { b2v = v[p]; }
            }
            if ((lk & 1) == 0) {
                const int o = (oprow0 >> 3) + (lk >> 1);
                const int n = nw + nf * 16 + lr;
                best[(size_t)o * N_ + n] = (unsigned char)bi;
                if (b2v - b1v < 0.03f) {
                    const unsigned idx = atomicAdd(wl_cnt, 1u);
                    if (idx < WL_CAP) wl[idx] = (unsigned)(o * N_ + n);
                }
            }
        }
    }
}

// ---------------------------------------------------------------------------
// Kernel A2: exact fp64 refine of near-tie (n,o) pairs (unchanged).
// ---------------------------------------------------------------------------
__global__ __launch_bounds__(256)
void refine_kernel(const float* __restrict__ ctx, const float* __restrict__ protos,
                   const unsigned* __restrict__ wl, const unsigned* __restrict__ wl_cnt,
                   unsigned char* __restrict__ best) {
    const unsigned cnt = min(*wl_cnt, WL_CAP);
    for (unsigned i = blockIdx.x * 256 + threadIdx.x; i < cnt; i += gridDim.x * 256) {
        const unsigned e = wl[i];
        const int n = (int)(e & (N_ - 1));
        const int o = (int)(e >> 13);
        const float* cr = ctx + (size_t)n * C_;
        double d1 = 1e300;
        int bi = 0;
        for (int p = 0; p < 8; ++p) {
            const float* pr = protos + ((size_t)o * 8 + p) * C_;
            double s = 0.0;
            for (int c = 0; c < C_; ++c) {
                const double pv = (double)pr[c];
                const double cv = (double)cr[c];
                s += pv * (pv - 2.0 * cv);
            }
            if (s < d1) { d1 = s; bi = p; }
        }
        best[(size_t)o * N_ + n] = (unsigned char)bi;
    }
}

// ---------------------------------------------------------------------------
// Kernel C: fp32 -> bf16 into the tiled-swizzled layout (validated round 5).
// ---------------------------------------------------------------------------
__global__ __launch_bounds__(256)
void convert_swz_kernel(const float* __restrict__ src, unsigned short* __restrict__ dst) {
    const int idx = blockIdx.x * 256 + threadIdx.x;  // 1,048,576 chunks
    const int rp = idx >> 8;
    const int t = (idx >> 3) & 31;
    const int j = idx & 7;
    const int c = j ^ (rp & 7);
    const int row = rp * 2 + (c >> 2);
    const int k0 = t * 32 + (c & 3) * 8;
    const float* sp = src + (size_t)row * I_ + k0;
    const float4 f0 = *(const float4*)(sp);
    const float4 f1 = *(const float4*)(sp + 4);
    ushort8 v;
    v[0] = __builtin_bit_cast(unsigned short, __float2bfloat16(f0.x));
    v[1] = __builtin_bit_cast(unsigned short, __float2bfloat16(f0.y));
    v[2] = __builtin_bit_cast(unsigned short, __float2bfloat16(f0.z));
    v[3] = __builtin_bit_cast(unsigned short, __float2bfloat16(f0.w));
    v[4] = __builtin_bit_cast(unsigned short, __float2bfloat16(f1.x));
    v[5] = __builtin_bit_cast(unsigned short, __float2bfloat16(f1.y));
    v[6] = __builtin_bit_cast(unsigned short, __float2bfloat16(f1.z));
    v[7] = __builtin_bit_cast(unsigned short, __float2bfloat16(f1.w));
    *(ushort8*)(dst + (size_t)idx * 8) = v;
}

// ---------------------------------------------------------------------------
// Kernel B: ring-2 bf16 MFMA GEMM, 2 blocks/CU. 256x256 tile, BK=32,
// 2 LDS buffers (64 KiB), 1 barrier/tile. Stage(t+1) issued at tile-t top,
// drained by vmcnt(0) at tile-t bottom (~0.8 tile cover + cross-block TLP).
// ---------------------------------------------------------------------------
__global__ __launch_bounds__(512, 4)
void gemm_gather_kernel(const unsigned short* __restrict__ Xb,
                        const unsigned short* __restrict__ Wb,
                        const float* __restrict__ bias,
                        const unsigned char* __restrict__ best,
                        float* __restrict__ out) {
    extern __shared__ unsigned short lds[];  // 2 x (A 16KB + B 16KB) = 64 KiB

    int wg = blockIdx.x;                     // 1024 blocks, %8==0 -> bijective
    wg = (wg & 7) * 128 + (wg >> 3);
    const int bx = wg & 31;
    const int by = wg >> 5;
    const int n0 = by * 256;
    const int col0 = bx * 256;

    const int tid = threadIdx.x;
    const int w = tid >> 6, l = tid & 63;
    const int wr = w >> 2;       // 0..1  (M half)
    const int wc = w & 3;        // 0..3  (N quarter)
    const int lr = l & 15;
    const int lk = l >> 4;

    #define STAGE(gsrc, rpg0, tt, ldsbase) do {                                     \
        _Pragma("unroll")                                                           \
        for (int _ld = 0; _ld < 2; ++_ld) {                                         \
            const int _L = _ld * 512 + tid;                                         \
            __builtin_amdgcn_global_load_lds(                                       \
                GLOBAL_AS((gsrc) + (((size_t)((rpg0) + (_L >> 3)) * 256 +           \
                                     (size_t)(tt) * 8 + (_L & 7)) * 8)),            \
                LDS_AS((ldsbase) + _L * 8), 16, 0, 0);                              \
        }                                                                           \
    } while (0)

    f32x4 acc[8][4];
    #pragma unroll
    for (int m = 0; m < 8; ++m)
        #pragma unroll
        for (int n = 0; n < 4; ++n) acc[m][n] = (f32x4)(0.f);

    const int rpgA = n0 >> 1;
    const int rpgB = col0 >> 1;

    // ---- prologue: stage tile 0 into buf0; drain ----
    STAGE(Xb, rpgA, 0, lds);
    STAGE(Wb, rpgB, 0, lds + 8192);
    asm volatile("s_waitcnt vmcnt(0)" ::: "memory");
    __builtin_amdgcn_sched_barrier(0);
    __builtin_amdgcn_s_barrier();

    bf16x8 af0[4], af1[4], bf[4];

    #define RD_A(dst, mbase, bb) do {                                                \
        _Pragma("unroll")                                                            \
        for (int _m = 0; _m < 4; ++_m) {                                             \
            const int _R = wr * 128 + ((mbase) + _m) * 16 + lr;                      \
            const int _rp = _R >> 1;                                                 \
            const int _j = (((_R & 1) << 2) + lk) ^ (_rp & 7);                       \
            dst[_m] = *(const bf16x8*)&lds[(bb) * 16384 + _rp * 64 + _j * 8];        \
        }                                                                            \
    } while (0)

    #define RD_B(bb) do {                                                            \
        _Pragma("unroll")                                                            \
        for (int _n = 0; _n < 4; ++_n) {                                             \
            const int _R = wc * 64 + _n * 16 + lr;                                   \
            const int _rp = _R >> 1;                                                 \
            const int _j = (((_R & 1) << 2) + lk) ^ (_rp & 7);                       \
            bf[_n] = *(const bf16x8*)&lds[(bb) * 16384 + 8192 + _rp * 64 + _j * 8];  \
        }                                                                            \
    } while (0)

    #define MFMA16(src, mbase) do {                                                  \
        __builtin_amdgcn_s_setprio(1);                                               \
        _Pragma("unroll")                                                            \
        for (int _m = 0; _m < 4; ++_m)                                               \
            _Pragma("unroll")                                                        \
            for (int _n = 0; _n < 4; ++_n)                                           \
                acc[(mbase) + _m][_n] =                                              \
                    __builtin_amdgcn_mfma_f32_16x16x32_bf16(                         \
                        src[_m], bf[_n], acc[(mbase) + _m][_n], 0, 0, 0);            \
        __builtin_amdgcn_s_setprio(0);                                               \
    } while (0)

    #pragma unroll 2
    for (int t = 0; t < 32; ++t) {
        const int b = t & 1;
        const int nb = b ^ 1;
        if (t + 1 < 32) {
            STAGE(Xb, rpgA, t + 1, lds + nb * 16384);
            STAGE(Wb, rpgB, t + 1, lds + nb * 16384 + 8192);
        }
        RD_A(af0, 0, b);
        RD_B(b);
        RD_A(af1, 4, b);
        asm volatile("s_waitcnt lgkmcnt(4)" ::: "memory");
        __builtin_amdgcn_sched_barrier(0);
        MFMA16(af0, 0);
        asm volatile("s_waitcnt lgkmcnt(0)" ::: "memory");
        __builtin_amdgcn_sched_barrier(0);
        MFMA16(af1, 4);
        asm volatile("s_waitcnt vmcnt(0)" ::: "memory");
        __builtin_amdgcn_sched_barrier(0);
        __builtin_amdgcn_s_barrier();
    }

    // ---- epilogue: fused argmin-gather + bias; u32 best loads ----
    const int nbase = n0 + wr * 128 + lk * 4;
    #pragma unroll
    for (int nf = 0; nf < 4; ++nf) {
        const int opcol = col0 + wc * 64 + nf * 16 + lr;
        const int o = opcol >> 3;
        const unsigned p = (unsigned)(opcol & 7);
        const float bv = bias[opcol];
        const unsigned char* brow = best + (size_t)o * N_ + nbase;
        #pragma unroll
        for (int m = 0; m < 8; ++m) {
            const unsigned b4 = *(const unsigned*)(brow + m * 16);
            #pragma unroll
            for (int j = 0; j < 4; ++j) {
                if (((b4 >> (j * 8)) & 255u) == p) {
                    const int n = nbase + m * 16 + j;
                    out[(size_t)n * O_ + o] = acc[m][nf][j] + bv;
                }
            }
        }
    }
    #undef STAGE
    #undef RD_A
    #undef RD_B
    #undef MFMA16
}

// ---------------------------------------------------------------------------
extern "C" void kernel_launch(void* const* d_in, const int* in_sizes, int n_in,
                              void* d_out, int out_size, void* d_ws, size_t ws_size,
                              hipStream_t stream) {
    const float* X      = (const float*)d_in[0];
    const float* ctx    = (const float*)d_in[1];
    const float* W      = (const float*)d_in[2];
    const float* bias   = (const float*)d_in[3];
    const float* protos = (const float*)d_in[4];
    float* out = (float*)d_out;

    char* ws = (char*)d_ws;
    unsigned char* best = (unsigned char*)ws;                         // 8 MiB
    float* psq = (float*)(ws + ((size_t)8 << 20));                    // 32 KiB
    unsigned short* Xb = (unsigned short*)(ws + ((size_t)9 << 20));   // 16 MiB
    unsigned short* Wb = (unsigned short*)(ws + ((size_t)25 << 20));  // 16 MiB
    unsigned* wl_cnt = (unsigned*)(ws + ((size_t)41 << 20));          // 4 B
    unsigned* wl = (unsigned*)(ws + ((size_t)41 << 20) + 256);        // 1 MiB

    // split-bf16 scratch lives in d_out (fully overwritten by gemm later)
    char* ob = (char*)d_out;
    unsigned short* ph = (unsigned short*)(ob + ((size_t)16 << 20));  // 1 MiB
    unsigned short* pl = (unsigned short*)(ob + ((size_t)17 << 20));  // 1 MiB
    unsigned short* ch = (unsigned short*)(ob + ((size_t)18 << 20));  // 1 MiB
    unsigned short* cl = (unsigned short*)(ob + ((size_t)19 << 20));  // 1 MiB

    hipFuncSetAttribute((const void*)gemm_gather_kernel,
                        hipFuncAttributeMaxDynamicSharedMemorySize, 65536);

    hipMemsetAsync(wl_cnt, 0, 4, stream);
    convert_swz_kernel<<<dim3(4096), dim3(256), 0, stream>>>(X, Xb);
    convert_swz_kernel<<<dim3(4096), dim3(256), 0, stream>>>(W, Wb);
    psq_kernel<<<dim3(32), dim3(256), 0, stream>>>(protos, psq);
    split_bf16_kernel<<<dim3(256), dim3(256), 0, stream>>>(protos, ph, pl);
    split_bf16_kernel<<<dim3(256), dim3(256), 0, stream>>>(ctx, ch, cl);
    argmin_mfma_kernel<<<dim3(OP_ / 128, N_ / 128), dim3(256), 0, stream>>>(ph, pl, ch, cl, psq, best, wl, wl_cnt);
    refine_kernel<<<dim3(64), dim3(256), 0, stream>>>(ctx, protos, wl, wl_cnt, best);
    gemm_gather_kernel<<<dim3(1024), dim3(512), 65536, stream>>>(Xb, Wb, bias, best, out);
}

// Round 7
// 1056.890 us; speedup vs baseline: 2.2694x; 2.2694x over previous
//
#include <hip/hip_runtime.h>
#include <hip/hip_bf16.h>

#define N_ 8192
#define I_ 1024
#define O_ 1024
#define P_ 8
#define C_ 64
#define OP_ (O_ * P_)
#define WL_CAP (1u << 18)

typedef float f32x4 __attribute__((ext_vector_type(4)));
typedef __bf16 bf16x8 __attribute__((ext_vector_type(8)));
typedef unsigned short ushort8 __attribute__((ext_vector_type(8)));

#define GLOBAL_AS(p) ((const __attribute__((address_space(1))) unsigned int*)(p))
#define LDS_AS(p) ((__attribute__((address_space(3))) unsigned int*)(p))

// ---------------------------------------------------------------------------
// Kernel A0: proto_sq[o*8+p] = sum_c protos[o,p,c]^2  (fp32, exact)
// ---------------------------------------------------------------------------
__global__ void psq_kernel(const float* __restrict__ protos, float* __restrict__ psq) {
    const int idx = blockIdx.x * 256 + threadIdx.x;  // 0..8191
    const float* pr = protos + (size_t)idx * C_;
    float s = 0.f;
    #pragma unroll
    for (int c = 0; c < C_; ++c) s = fmaf(pr[c], pr[c], s);
    psq[idx] = s;
}

// ---------------------------------------------------------------------------
// Kernel S: split fp32 -> bf16 hi + lo (x = hi + lo + O(2^-17 x)).
// ---------------------------------------------------------------------------
__global__ __launch_bounds__(256)
void split_bf16_kernel(const float* __restrict__ src, unsigned short* __restrict__ hi,
                       unsigned short* __restrict__ lo) {
    const int idx = blockIdx.x * 256 + threadIdx.x;
    const float* sp = src + (size_t)idx * 8;
    const float4 f0 = *(const float4*)(sp);
    const float4 f1 = *(const float4*)(sp + 4);
    float f[8] = {f0.x, f0.y, f0.z, f0.w, f1.x, f1.y, f1.z, f1.w};
    ushort8 vh, vl;
    #pragma unroll
    for (int e = 0; e < 8; ++e) {
        const __hip_bfloat16 h = __float2bfloat16(f[e]);
        const __hip_bfloat16 l = __float2bfloat16(f[e] - __bfloat162float(h));
        vh[e] = __builtin_bit_cast(unsigned short, h);
        vl[e] = __builtin_bit_cast(unsigned short, l);
    }
    *(ushort8*)(hi + (size_t)idx * 8) = vh;
    *(ushort8*)(lo + (size_t)idx * 8) = vl;
}

// ---------------------------------------------------------------------------
// Kernel A: argmin via split-bf16 MFMA (validated round 6).
// ---------------------------------------------------------------------------
__global__ __launch_bounds__(256, 2)
void argmin_mfma_kernel(const unsigned short* __restrict__ ph, const unsigned short* __restrict__ pl,
                        const unsigned short* __restrict__ ch, const unsigned short* __restrict__ cl,
                        const float* __restrict__ psq, unsigned char* __restrict__ best,
                        unsigned* __restrict__ wl, unsigned* __restrict__ wl_cnt) {
    const int tid = threadIdx.x;
    const int w = tid >> 6, l = tid & 63;
    const int op0 = blockIdx.x * 128;
    const int nw = blockIdx.y * 128 + w * 32;
    const int lr = l & 15, lk = l >> 4;

    f32x4 acc[8][2];
    #pragma unroll
    for (int of = 0; of < 8; ++of)
        #pragma unroll
        for (int nf = 0; nf < 2; ++nf) acc[of][nf] = (f32x4)(0.f);

    #pragma unroll
    for (int ks = 0; ks < 2; ++ks) {
        const int ko = ks * 32 + lk * 8;
        bf16x8 Ah[8], Al[8], Bh[2], Bl[2];
        #pragma unroll
        for (int of = 0; of < 8; ++of) {
            const size_t r = (size_t)(op0 + of * 16 + lr) * C_ + ko;
            Ah[of] = *(const bf16x8*)(ph + r);
            Al[of] = *(const bf16x8*)(pl + r);
        }
        #pragma unroll
        for (int nf = 0; nf < 2; ++nf) {
            const size_t r = (size_t)(nw + nf * 16 + lr) * C_ + ko;
            Bh[nf] = *(const bf16x8*)(ch + r);
            Bl[nf] = *(const bf16x8*)(cl + r);
        }
        #pragma unroll
        for (int of = 0; of < 8; ++of)
            #pragma unroll
            for (int nf = 0; nf < 2; ++nf) {
                acc[of][nf] = __builtin_amdgcn_mfma_f32_16x16x32_bf16(Ah[of], Bh[nf], acc[of][nf], 0, 0, 0);
                acc[of][nf] = __builtin_amdgcn_mfma_f32_16x16x32_bf16(Ah[of], Bl[nf], acc[of][nf], 0, 0, 0);
                acc[of][nf] = __builtin_amdgcn_mfma_f32_16x16x32_bf16(Al[of], Bh[nf], acc[of][nf], 0, 0, 0);
            }
    }

    #pragma unroll
    for (int of = 0; of < 8; ++of) {
        const int oprow0 = op0 + of * 16;
        const f32x4 ps = *(const f32x4*)(psq + oprow0 + lk * 4);
        #pragma unroll
        for (int nf = 0; nf < 2; ++nf) {
            float d[4], e[4];
            #pragma unroll
            for (int j = 0; j < 4; ++j) {
                d[j] = fmaf(-2.f, acc[of][nf][j], ps[j]);
                e[j] = __shfl_xor(d[j], 16, 64);
            }
            float v[8];
            const int po = (lk & 1) * 4;
            #pragma unroll
            for (int j = 0; j < 4; ++j) { v[po + j] = d[j]; v[(po ^ 4) + j] = e[j]; }
            float b1v = 3.4e38f, b2v = 3.4e38f;
            int bi = 0;
            #pragma unroll
            for (int p = 0; p < 8; ++p) {
                if (v[p] < b1v) { b2v = b1v; b1v = v[p]; bi = p; }
                else if (v[p] < b2v) { b2v = v[p]; }
            }
            if ((lk & 1) == 0) {
                const int o = (oprow0 >> 3) + (lk >> 1);
                const int n = nw + nf * 16 + lr;
                best[(size_t)o * N_ + n] = (unsigned char)bi;
                if (b2v - b1v < 0.03f) {
                    const unsigned idx = atomicAdd(wl_cnt, 1u);
                    if (idx < WL_CAP) wl[idx] = (unsigned)(o * N_ + n);
                }
            }
        }
    }
}

// ---------------------------------------------------------------------------
// Kernel A2: exact fp64 refine of near-tie (n,o) pairs (unchanged).
// ---------------------------------------------------------------------------
__global__ __launch_bounds__(256)
void refine_kernel(const float* __restrict__ ctx, const float* __restrict__ protos,
                   const unsigned* __restrict__ wl, const unsigned* __restrict__ wl_cnt,
                   unsigned char* __restrict__ best) {
    const unsigned cnt = min(*wl_cnt, WL_CAP);
    for (unsigned i = blockIdx.x * 256 + threadIdx.x; i < cnt; i += gridDim.x * 256) {
        const unsigned e = wl[i];
        const int n = (int)(e & (N_ - 1));
        const int o = (int)(e >> 13);
        const float* cr = ctx + (size_t)n * C_;
        double d1 = 1e300;
        int bi = 0;
        for (int p = 0; p < 8; ++p) {
            const float* pr = protos + ((size_t)o * 8 + p) * C_;
            double s = 0.0;
            for (int c = 0; c < C_; ++c) {
                const double pv = (double)pr[c];
                const double cv = (double)cr[c];
                s += pv * (pv - 2.0 * cv);
            }
            if (s < d1) { d1 = s; bi = p; }
        }
        best[(size_t)o * N_ + n] = (unsigned char)bi;
    }
}

// ---------------------------------------------------------------------------
// Kernel C: fp32 -> bf16 into half-tile-blocked, row-XOR-swizzled layout.
// dst chunk idx = (((rb*16+kt)*2+h)*1024 + L)*8 ushorts; L=(Lr,j), j=0..7.
// Stored logical chunk c = j ^ (Lr&7) of row Rlocal:
//   LAYOUT 0 (A, 64-row halves): Rlocal = (Lr&63) + ((Lr&64)<<1) + h*64
//   LAYOUT 1 (B, 32-row halves): Rlocal = (Lr>>5)*64 + h*32 + (Lr&31)
// (Rlocal&7 == Lr&7 in both, matching the gemm's read-side XOR on lr&7.)
// ---------------------------------------------------------------------------
template<int LAYOUT>
__global__ __launch_bounds__(256)
void convert_tiled_kernel(const float* __restrict__ src, unsigned short* __restrict__ dst) {
    const int idx = blockIdx.x * 256 + threadIdx.x;  // 1,048,576 chunks
    const int rb = idx >> 15;
    const int r = idx & 32767;
    const int kt = r >> 11;
    const int h = (r >> 10) & 1;
    const int L = r & 1023;
    const int Lr = L >> 3;
    const int j = L & 7;
    const int c = j ^ (Lr & 7);
    int Rlocal;
    if (LAYOUT == 0) Rlocal = (Lr & 63) + ((Lr & 64) << 1) + h * 64;
    else             Rlocal = ((Lr >> 5) << 6) + h * 32 + (Lr & 31);
    const int gR = rb * 256 + Rlocal;
    const int k0 = kt * 64 + c * 8;
    const float* sp = src + (size_t)gR * I_ + k0;
    const float4 f0 = *(const float4*)(sp);
    const float4 f1 = *(const float4*)(sp + 4);
    ushort8 v;
    v[0] = __builtin_bit_cast(unsigned short, __float2bfloat16(f0.x));
    v[1] = __builtin_bit_cast(unsigned short, __float2bfloat16(f0.y));
    v[2] = __builtin_bit_cast(unsigned short, __float2bfloat16(f0.z));
    v[3] = __builtin_bit_cast(unsigned short, __float2bfloat16(f0.w));
    v[4] = __builtin_bit_cast(unsigned short, __float2bfloat16(f1.x));
    v[5] = __builtin_bit_cast(unsigned short, __float2bfloat16(f1.y));
    v[6] = __builtin_bit_cast(unsigned short, __float2bfloat16(f1.z));
    v[7] = __builtin_bit_cast(unsigned short, __float2bfloat16(f1.w));
    *(ushort8*)(dst + (size_t)idx * 8) = v;
}

// ---------------------------------------------------------------------------
// Kernel B: 256x256 phase-pipelined bf16 MFMA GEMM (m201-derived) + gather.
// BK=64, 16 K-tiles x 4 phases; 2 LDS bufs (128 KiB) in half-tiles
// {Aa,Ab}={m03,m47}-rows, {Ba,Bb}={n01,n23}-rows. Per phase: pre-barrier
// ds_reads (hidden under prior MFMA), stage 1 half (kt+1), vmcnt(4) [drains
// the half read next phase], 1 barrier, lgkmcnt(0), 16 MFMA. Quadrant path
// m03n01 -> m03n23 -> m47n23 -> m47n01; stage order Ba,Aa,Bb,Ab. All WAR
// separations >= 1 barrier; every staged half has >= 3 phases in flight.
// ---------------------------------------------------------------------------
__global__ __launch_bounds__(512, 1)
void gemm_gather_kernel(const unsigned short* __restrict__ Xb,
                        const unsigned short* __restrict__ Wb,
                        const float* __restrict__ bias,
                        const unsigned char* __restrict__ best,
                        float* __restrict__ out) {
    extern __shared__ unsigned short lds[];  // 2 x (A 16384 + B 16384) ushort = 128 KiB

    int wg = blockIdx.x;                     // 1024 blocks, %8==0 -> bijective
    wg = (wg & 7) * 128 + (wg >> 3);
    const int bx = wg & 31;
    const int by = wg >> 5;
    const int n0 = by * 256;
    const int col0 = bx * 256;

    const int tid = threadIdx.x;
    const int w = tid >> 6, l = tid & 63;
    const int wr = w >> 2, wc = w & 3;
    const int lr = l & 15, lk = l >> 4;
    const int lx = lr & 7;

    const unsigned short* Xrb = Xb + (size_t)(n0 >> 8) * 262144;
    const unsigned short* Wrb = Wb + (size_t)(col0 >> 8) * 262144;

    // stage one half-tile (1024 chunks): 2 x global_load_lds(16B)/thread
    #define STAGE(src, ktt, h, ldsofs) do {                                          \
        const unsigned short* _g = (src) + ((size_t)(ktt) * 2 + (h)) * 8192;         \
        __builtin_amdgcn_global_load_lds(GLOBAL_AS(_g + (size_t)tid * 8),            \
            LDS_AS(lds + (ldsofs) + tid * 8), 16, 0, 0);                             \
        __builtin_amdgcn_global_load_lds(GLOBAL_AS(_g + (size_t)(tid + 512) * 8),    \
            LDS_AS(lds + (ldsofs) + (tid + 512) * 8), 16, 0, 0);                     \
    } while (0)

    #define VMCNT4() do { asm volatile("s_waitcnt vmcnt(4)" ::: "memory");           \
        __builtin_amdgcn_sched_barrier(0); } while (0)
    #define VMCNT2() do { asm volatile("s_waitcnt vmcnt(2)" ::: "memory");           \
        __builtin_amdgcn_sched_barrier(0); } while (0)
    #define VMCNT0() do { asm volatile("s_waitcnt vmcnt(0)" ::: "memory");           \
        __builtin_amdgcn_sched_barrier(0); } while (0)
    #define LGKM0() do { asm volatile("s_waitcnt lgkmcnt(0)" ::: "memory");          \
        __builtin_amdgcn_sched_barrier(0); } while (0)

    f32x4 acc[8][4];
    #pragma unroll
    for (int m = 0; m < 8; ++m)
        #pragma unroll
        for (int n = 0; n < 4; ++n) acc[m][n] = (f32x4)(0.f);

    // A read: 4 m-frags x 2 k-halves from buf bb
    #define RD_A(dst, mbase, bb) do {                                                \
        _Pragma("unroll")                                                            \
        for (int _m = 0; _m < 4; ++_m) {                                             \
            const int _R = wr * 128 + ((mbase) + _m) * 16 + lr;                      \
            const int _h = (_R >> 6) & 1;                                            \
            const int _Lr = (_R & 63) + ((_R & 128) >> 1);                           \
            _Pragma("unroll")                                                        \
            for (int _k = 0; _k < 2; ++_k) {                                         \
                const int _s = (_k * 4 + lk) ^ lx;                                   \
                dst[_m][_k] = *(const bf16x8*)&lds[(bb) * 32768 + _h * 8192 +        \
                                                   _Lr * 64 + _s * 8];               \
            }                                                                        \
        }                                                                            \
    } while (0)

    // B read: 2 n-frags x 2 k-halves from buf bb
    #define RD_B(dst, nbase, bb) do {                                                \
        _Pragma("unroll")                                                            \
        for (int _n = 0; _n < 2; ++_n) {                                             \
            const int _R = wc * 64 + ((nbase) + _n) * 16 + lr;                       \
            const int _h = (_R >> 5) & 1;                                            \
            const int _Lr = ((_R >> 6) << 5) + (_R & 31);                            \
            _Pragma("unroll")                                                        \
            for (int _k = 0; _k < 2; ++_k) {                                         \
                const int _s = (_k * 4 + lk) ^ lx;                                   \
                dst[_n][_k] = *(const bf16x8*)&lds[(bb) * 32768 + 16384 +            \
                                                   _h * 8192 + _Lr * 64 + _s * 8];   \
            }                                                                        \
        }                                                                            \
    } while (0)

    #define MFMA16(AF, BF, MB, NB) do {                                              \
        __builtin_amdgcn_s_setprio(1);                                               \
        _Pragma("unroll")                                                            \
        for (int _m = 0; _m < 4; ++_m)                                               \
            _Pragma("unroll")                                                        \
            for (int _n = 0; _n < 2; ++_n)                                           \
                _Pragma("unroll")                                                    \
                for (int _k = 0; _k < 2; ++_k)                                       \
                    acc[(MB) + _m][(NB) + _n] =                                      \
                        __builtin_amdgcn_mfma_f32_16x16x32_bf16(                     \
                            AF[_m][_k], BF[_n][_k], acc[(MB) + _m][(NB) + _n], 0, 0, 0); \
        __builtin_amdgcn_s_setprio(0);                                               \
    } while (0)

    bf16x8 af[4][2], bfa[2][2], bfb[2][2];

    // ---- prologue: stage kt0 {Aa,Ba,Bb,Ab}; drain Aa0,Ba0 ----
    STAGE(Xrb, 0, 0, 0);              // A-alpha(0)
    STAGE(Wrb, 0, 0, 16384);          // B-alpha(0)
    STAGE(Wrb, 0, 1, 16384 + 8192);   // B-beta(0)
    STAGE(Xrb, 0, 1, 8192);           // A-beta(0)
    VMCNT4();
    __builtin_amdgcn_s_barrier();

    #pragma unroll 1
    for (int kt = 0; kt < 15; ++kt) {
        const int b = kt & 1, nb = b ^ 1;
        const int nbo = nb * 32768;
        // P1: read Aa(m0-3)+Ba(n0-1); stage Ba(kt+1)
        RD_A(af, 0, b);
        RD_B(bfa, 0, b);
        STAGE(Wrb, kt + 1, 0, nbo + 16384);
        VMCNT4();
        __builtin_amdgcn_s_barrier();
        LGKM0();
        MFMA16(af, bfa, 0, 0);
        // P2: read Bb(n2-3); stage Aa(kt+1)
        RD_B(bfb, 2, b);
        STAGE(Xrb, kt + 1, 0, nbo);
        VMCNT4();
        __builtin_amdgcn_s_barrier();
        LGKM0();
        MFMA16(af, bfb, 0, 2);
        // P3: read Ab(m4-7); stage Bb(kt+1)
        RD_A(af, 4, b);
        STAGE(Wrb, kt + 1, 1, nbo + 16384 + 8192);
        VMCNT4();
        __builtin_amdgcn_s_barrier();
        LGKM0();
        MFMA16(af, bfb, 4, 2);
        // P4: re-read Ba(n0-1); stage Ab(kt+1)
        RD_B(bfa, 0, b);
        STAGE(Xrb, kt + 1, 1, nbo + 8192);
        VMCNT4();
        __builtin_amdgcn_s_barrier();
        LGKM0();
        MFMA16(af, bfa, 4, 0);
    }
    // ---- tail kt=15 (buf 1, no staging; drain Bb15 then Ab15) ----
    {
        RD_A(af, 0, 1);
        RD_B(bfa, 0, 1);
        VMCNT2();
        __builtin_amdgcn_s_barrier();
        LGKM0();
        MFMA16(af, bfa, 0, 0);
        RD_B(bfb, 2, 1);
        VMCNT0();
        __builtin_amdgcn_s_barrier();
        LGKM0();
        MFMA16(af, bfb, 0, 2);
        RD_A(af, 4, 1);
        LGKM0();
        MFMA16(af, bfb, 4, 2);
        RD_B(bfa, 0, 1);
        LGKM0();
        MFMA16(af, bfa, 4, 0);
    }

    // ---- epilogue: fused argmin-gather + bias; u32 best loads ----
    const int nbase = n0 + wr * 128 + lk * 4;
    #pragma unroll
    for (int nf = 0; nf < 4; ++nf) {
        const int opcol = col0 + wc * 64 + nf * 16 + lr;
        const int o = opcol >> 3;
        const unsigned p = (unsigned)(opcol & 7);
        const float bv = bias[opcol];
        const unsigned char* brow = best + (size_t)o * N_ + nbase;
        #pragma unroll
        for (int m = 0; m < 8; ++m) {
            const unsigned b4 = *(const unsigned*)(brow + m * 16);
            #pragma unroll
            for (int j = 0; j < 4; ++j) {
                if (((b4 >> (j * 8)) & 255u) == p) {
                    const int n = nbase + m * 16 + j;
                    out[(size_t)n * O_ + o] = acc[m][nf][j] + bv;
                }
            }
        }
    }
    #undef STAGE
    #undef RD_A
    #undef RD_B
    #undef MFMA16
    #undef VMCNT4
    #undef VMCNT2
    #undef VMCNT0
    #undef LGKM0
}

// ---------------------------------------------------------------------------
extern "C" void kernel_launch(void* const* d_in, const int* in_sizes, int n_in,
                              void* d_out, int out_size, void* d_ws, size_t ws_size,
                              hipStream_t stream) {
    const float* X      = (const float*)d_in[0];
    const float* ctx    = (const float*)d_in[1];
    const float* W      = (const float*)d_in[2];
    const float* bias   = (const float*)d_in[3];
    const float* protos = (const float*)d_in[4];
    float* out = (float*)d_out;

    char* ws = (char*)d_ws;
    unsigned char* best = (unsigned char*)ws;                         // 8 MiB
    float* psq = (float*)(ws + ((size_t)8 << 20));                    // 32 KiB
    unsigned short* Xb = (unsigned short*)(ws + ((size_t)9 << 20));   // 16 MiB
    unsigned short* Wb = (unsigned short*)(ws + ((size_t)25 << 20));  // 16 MiB
    unsigned* wl_cnt = (unsigned*)(ws + ((size_t)41 << 20));          // 4 B
    unsigned* wl = (unsigned*)(ws + ((size_t)41 << 20) + 256);        // 1 MiB

    // split-bf16 scratch lives in d_out (fully overwritten by gemm later)
    char* ob = (char*)d_out;
    unsigned short* ph = (unsigned short*)(ob + ((size_t)16 << 20));  // 1 MiB
    unsigned short* pl = (unsigned short*)(ob + ((size_t)17 << 20));  // 1 MiB
    unsigned short* ch = (unsigned short*)(ob + ((size_t)18 << 20));  // 1 MiB
    unsigned short* cl = (unsigned short*)(ob + ((size_t)19 << 20));  // 1 MiB

    hipFuncSetAttribute((const void*)gemm_gather_kernel,
                        hipFuncAttributeMaxDynamicSharedMemorySize, 131072);

    hipMemsetAsync(wl_cnt, 0, 4, stream);
    convert_tiled_kernel<0><<<dim3(4096), dim3(256), 0, stream>>>(X, Xb);
    convert_tiled_kernel<1><<<dim3(4096), dim3(256), 0, stream>>>(W, Wb);
    psq_kernel<<<dim3(32), dim3(256), 0, stream>>>(protos, psq);
    split_bf16_kernel<<<dim3(256), dim3(256), 0, stream>>>(protos, ph, pl);
    split_bf16_kernel<<<dim3(256), dim3(256), 0, stream>>>(ctx, ch, cl);
    argmin_mfma_kernel<<<dim3(OP_ / 128, N_ / 128), dim3(256), 0, stream>>>(ph, pl, ch, cl, psq, best, wl, wl_cnt);
    refine_kernel<<<dim3(64), dim3(256), 0, stream>>>(ctx, protos, wl, wl_cnt, best);
    gemm_gather_kernel<<<dim3(1024), dim3(512), 131072, stream>>>(Xb, Wb, bias, best, out);
}